// Round 2
// baseline (3544.641 us; speedup 1.0000x reference)
//
#include <hip/hip_runtime.h>

// ---------------------------------------------------------------------------
// OHEM cross-entropy, 3-kernel pipeline:
//   losses[i] = log(sum_j exp(pred[i,j])) - pred[i, target[i]]   (>=0, clamped)
//   answer    = mean of the top keep_num = int(0.7*N) losses
// Top-k sum via a 65536-bin histogram on the top 16 bits of the float pattern
// (monotone for non-negative floats). Bins above the pivot are summed exactly
// (per-bin double sums); the partial pivot bin uses the bin average —
// error <= r_in * binwidth / k ~ 1e-3, far under the 0.117 threshold.
// ---------------------------------------------------------------------------

#define NBINS 65536

__global__ __launch_bounds__(256) void init_k(uint4* ws) {
    // zero cnt (65536 u32) + dsum (65536 f64) = 768 KB = 49152 uint4
    int stride = gridDim.x * blockDim.x;
    for (int i = blockIdx.x * blockDim.x + threadIdx.x; i < 49152; i += stride)
        ws[i] = make_uint4(0u, 0u, 0u, 0u);
}

// grid-stride; each wave handles 2 rows per iteration: lanes 0-31 -> row r0,
// lanes 32-63 -> row r0+1; float4 per lane (16 B, fully coalesced 1 KB/wave).
__global__ __launch_bounds__(256) void loss_hist_k(const float* __restrict__ pred,
                                                   const int* __restrict__ target,
                                                   unsigned* __restrict__ cnt,
                                                   double* __restrict__ dsum, int N) {
    int gtid = blockIdx.x * blockDim.x + threadIdx.x;
    int wave = gtid >> 6;
    int lane = threadIdx.x & 63;
    int half = lane >> 5;          // which row of the pair
    int l32  = lane & 31;
    int nw   = (gridDim.x * blockDim.x) >> 6;

    #pragma unroll 2
    for (int r0 = wave * 2; r0 < N; r0 += nw * 2) {
        int row = r0 + half;
        if (row < N) {
            float4 v = ((const float4*)(pred + (size_t)row * 128))[l32];
            float e = __expf(v.x) + __expf(v.y) + __expf(v.z) + __expf(v.w);
            #pragma unroll
            for (int off = 1; off < 32; off <<= 1) e += __shfl_xor(e, off);
            // e = full row sum-of-exp in every lane of this half-wave
            int tg = target[row];  // uniform within the half-wave
            float xs = (tg & 2) ? ((tg & 1) ? v.w : v.z)
                                : ((tg & 1) ? v.y : v.x);
            float xt = __shfl(xs, (tg >> 2) + (half << 5));
            float loss = fmaxf(__logf(e) - xt, 0.0f);   // >=0 keeps uint order valid
            if (l32 == 0) {
                unsigned b = __float_as_uint(loss) >> 16;
                atomicAdd(&cnt[b], 1u);
                atomicAdd(&dsum[b], (double)loss);
            }
        }
    }
}

// single block: hierarchical suffix scan over 65536 bins, resolve pivot,
// write final mean.
__global__ __launch_bounds__(256) void scan_k(const unsigned* __restrict__ cnt,
                                              const double* __restrict__ dsum,
                                              float* __restrict__ out, int K) {
    __shared__ unsigned ccnt[256];
    __shared__ double   csum[256];
    __shared__ unsigned bcnt[256];
    __shared__ double   bsum[256];
    __shared__ int      sh_chunk;
    __shared__ unsigned sh_above_c;
    __shared__ double   sh_above_s;

    int t    = threadIdx.x;
    int wave = t >> 6;
    int lane = t & 63;

    // phase 1: per-chunk (256 bins) totals; wave-cooperative, coalesced
    for (int c = wave * 64; c < wave * 64 + 64; c++) {
        uint4 cv = ((const uint4*)cnt)[c * 64 + lane];
        unsigned cc = cv.x + cv.y + cv.z + cv.w;
        double2 sa = ((const double2*)dsum)[c * 128 + lane * 2];
        double2 sb = ((const double2*)dsum)[c * 128 + lane * 2 + 1];
        double ss = sa.x + sa.y + sb.x + sb.y;
        #pragma unroll
        for (int off = 1; off < 64; off <<= 1) {
            cc += __shfl_xor(cc, off);
            ss += __shfl_xor(ss, off);
        }
        if (lane == 0) { ccnt[c] = cc; csum[c] = ss; }
    }
    __syncthreads();

    // phase 2: inclusive suffix scan (from top) over 256 chunks, in place
    #pragma unroll
    for (int step = 1; step < 256; step <<= 1) {
        unsigned vc = (t + step < 256) ? ccnt[t + step] : 0u;
        double   vs = (t + step < 256) ? csum[t + step] : 0.0;
        __syncthreads();
        ccnt[t] += vc;
        csum[t] += vs;
        __syncthreads();
    }

    // phase 3: locate the chunk containing rank K (counting from the top)
    {
        unsigned incl  = ccnt[t];
        unsigned above = (t < 255) ? ccnt[t + 1] : 0u;
        if (incl >= (unsigned)K && above < (unsigned)K) {
            sh_chunk   = t;
            sh_above_c = above;
            sh_above_s = (t < 255) ? csum[t + 1] : 0.0;
        }
    }
    __syncthreads();

    // phase 4: load pivot chunk's bins, serial top-down resolve by thread 0
    int c = sh_chunk;
    bcnt[t] = cnt[c * 256 + t];
    bsum[t] = dsum[c * 256 + t];
    __syncthreads();
    if (t == 0) {
        unsigned acc = sh_above_c;
        double  accs = sh_above_s;
        for (int b = 255; b >= 0; b--) {
            unsigned nc = acc + bcnt[b];
            if (nc >= (unsigned)K) {
                unsigned r  = (unsigned)K - acc;         // values taken from this bin
                double  avg = bsum[b] / (double)bcnt[b]; // bcnt[b] >= r >= 1 here
                out[0] = (float)((accs + (double)r * avg) / (double)K);
                break;
            }
            acc  = nc;
            accs += bsum[b];
        }
    }
}

extern "C" void kernel_launch(void* const* d_in, const int* in_sizes, int n_in,
                              void* d_out, int out_size, void* d_ws, size_t ws_size,
                              hipStream_t stream) {
    const float* pred   = (const float*)d_in[0];
    const int*   target = (const int*)d_in[1];
    int N = in_sizes[1];                    // pred is [N,128]
    int k = (int)((double)N * 0.7);         // matches python int(N*0.7)

    unsigned* cnt  = (unsigned*)d_ws;
    double*   dsum = (double*)((char*)d_ws + (size_t)NBINS * 4);

    init_k<<<64, 256, 0, stream>>>((uint4*)d_ws);
    loss_hist_k<<<2048, 256, 0, stream>>>(pred, target, cnt, dsum, N);
    scan_k<<<1, 256, 0, stream>>>(cnt, dsum, (float*)d_out, k);
}

// Round 3
// 725.853 us; speedup vs baseline: 4.8834x; 4.8834x over previous
//
#include <hip/hip_runtime.h>

// ---------------------------------------------------------------------------
// OHEM cross-entropy, 3 kernels, zero global atomics:
//   1) loss_hist_k: loss[i] = log(sum exp(pred[i,:])) - pred[i,target[i]],
//      binned (linear, [0,16), width 1/256) into a per-block LDS histogram
//      (u32 cnt + f32 sum), flushed by plain stores to a private slab.
//   2) reduce_k: column-sum the 512 private histograms -> cnt[4096], dsum[4096].
//   3) scan_k: suffix-scan from the top, pivot bin, mean of top k via
//      exact sums above pivot + r * (pivot bin average).
// ---------------------------------------------------------------------------

#define NB 4096
#define G  512
#define SCALE 256.0f

__global__ __launch_bounds__(256) void loss_hist_k(const float* __restrict__ pred,
                                                   const int* __restrict__ target,
                                                   unsigned* __restrict__ priv_cnt,
                                                   float* __restrict__ priv_sum,
                                                   int N) {
    __shared__ unsigned hc[NB];
    __shared__ float    hs[NB];
    int t = threadIdx.x;
    for (int i = t; i < NB; i += 256) { hc[i] = 0u; hs[i] = 0.0f; }
    __syncthreads();

    int gtid = blockIdx.x * 256 + t;
    int wave = gtid >> 6;
    int lane = t & 63;
    int g4   = lane >> 4;              // which row of the quad (16 lanes per row)
    int l16  = lane & 15;
    int nw   = (gridDim.x * 256) >> 6; // total waves

    for (int r = wave * 8; r < N; r += nw * 8) {
        // clamp rows so all lanes stay active for shuffles; commit is guarded
        int rowA = r + g4;       if (rowA > N - 1) rowA = N - 1;
        int rowB = r + 4 + g4;   if (rowB > N - 1) rowB = N - 1;
        const float4* pa = (const float4*)(pred + (size_t)rowA * 128);
        const float4* pb = (const float4*)(pred + (size_t)rowB * 128);
        float4 a1 = pa[l16], a2 = pa[l16 + 16];   // cols l16*4..+3, 64+l16*4..+3
        float4 b1 = pb[l16], b2 = pb[l16 + 16];
        int ta = target[rowA], tb = target[rowB];

        float ea = __expf(a1.x) + __expf(a1.y) + __expf(a1.z) + __expf(a1.w)
                 + __expf(a2.x) + __expf(a2.y) + __expf(a2.z) + __expf(a2.w);
        float eb = __expf(b1.x) + __expf(b1.y) + __expf(b1.z) + __expf(b1.w)
                 + __expf(b2.x) + __expf(b2.y) + __expf(b2.z) + __expf(b2.w);
        #pragma unroll
        for (int off = 1; off < 16; off <<= 1) {
            ea += __shfl_xor(ea, off);
            eb += __shfl_xor(eb, off);
        }
        // fetch pred[row, target[row]]: owner lane (ta>>2)&15 in this 16-group
        float4 sa = (ta & 64) ? a2 : a1;
        float xsa = (ta & 2) ? ((ta & 1) ? sa.w : sa.z)
                             : ((ta & 1) ? sa.y : sa.x);
        float xta = __shfl(xsa, (lane & 48) + ((ta >> 2) & 15));
        float4 sb = (tb & 64) ? b2 : b1;
        float xsb = (tb & 2) ? ((tb & 1) ? sb.w : sb.z)
                             : ((tb & 1) ? sb.y : sb.x);
        float xtb = __shfl(xsb, (lane & 48) + ((tb >> 2) & 15));

        if (l16 == 0) {
            float la = fmaxf(__logf(ea) - xta, 0.0f);
            float lb = fmaxf(__logf(eb) - xtb, 0.0f);
            if (r + g4 < N) {
                int ba = min((int)(la * SCALE), NB - 1);
                atomicAdd(&hc[ba], 1u);
                atomicAdd(&hs[ba], la);
            }
            if (r + 4 + g4 < N) {
                int bb = min((int)(lb * SCALE), NB - 1);
                atomicAdd(&hc[bb], 1u);
                atomicAdd(&hs[bb], lb);
            }
        }
    }
    __syncthreads();
    unsigned base = blockIdx.x * NB;
    for (int i = t; i < NB; i += 256) {
        priv_cnt[base + i] = hc[i];
        priv_sum[base + i] = hs[i];
    }
}

__global__ __launch_bounds__(256) void reduce_k(const unsigned* __restrict__ priv_cnt,
                                                const float* __restrict__ priv_sum,
                                                unsigned* __restrict__ cnt,
                                                double* __restrict__ dsum) {
    int b = blockIdx.x * 256 + threadIdx.x;   // 16 blocks x 256 = 4096 bins
    unsigned c = 0;
    double s = 0.0;
    #pragma unroll 4
    for (int g = 0; g < G; g++) {
        c += priv_cnt[(size_t)g * NB + b];
        s += (double)priv_sum[(size_t)g * NB + b];
    }
    cnt[b] = c;
    dsum[b] = s;
}

__global__ __launch_bounds__(256) void scan_k(const unsigned* __restrict__ cnt,
                                              const double* __restrict__ dsum,
                                              float* __restrict__ out, int K) {
    __shared__ unsigned sc[256];
    __shared__ double   ss[256];
    __shared__ int      pivot;
    __shared__ unsigned above_c;
    __shared__ double   above_s;
    int t = threadIdx.x;
    unsigned c = 0;
    double s = 0.0;
    #pragma unroll
    for (int j = 0; j < 16; j++) { c += cnt[t * 16 + j]; s += dsum[t * 16 + j]; }
    sc[t] = c;
    ss[t] = s;
    __syncthreads();
    #pragma unroll
    for (int step = 1; step < 256; step <<= 1) {
        unsigned vc = (t + step < 256) ? sc[t + step] : 0u;
        double   vs = (t + step < 256) ? ss[t + step] : 0.0;
        __syncthreads();
        sc[t] += vc;
        ss[t] += vs;
        __syncthreads();
    }
    unsigned incl = sc[t];
    unsigned abv  = (t < 255) ? sc[t + 1] : 0u;
    if (incl >= (unsigned)K && abv < (unsigned)K) {
        pivot   = t;
        above_c = abv;
        above_s = (t < 255) ? ss[t + 1] : 0.0;
    }
    __syncthreads();
    if (t == 0) {
        int pc = pivot;
        unsigned acc = above_c;
        double  accs = above_s;
        for (int b = 15; b >= 0; b--) {
            unsigned cb = cnt[pc * 16 + b];
            if (acc + cb >= (unsigned)K) {
                unsigned rIn = (unsigned)K - acc;
                double   avg = dsum[pc * 16 + b] / (double)cb;
                out[0] = (float)((accs + (double)rIn * avg) / (double)K);
                return;
            }
            acc  += cb;
            accs += dsum[pc * 16 + b];
        }
    }
}

extern "C" void kernel_launch(void* const* d_in, const int* in_sizes, int n_in,
                              void* d_out, int out_size, void* d_ws, size_t ws_size,
                              hipStream_t stream) {
    const float* pred   = (const float*)d_in[0];
    const int*   target = (const int*)d_in[1];
    int N = in_sizes[1];                    // pred is [N,128]
    int K = (int)((double)N * 0.7);         // matches python int(N*0.7)

    unsigned* priv_cnt = (unsigned*)d_ws;                                   // 8 MB
    float*    priv_sum = (float*)((char*)d_ws + (size_t)G * NB * 4);        // 8 MB
    unsigned* cnt      = (unsigned*)((char*)d_ws + (size_t)2 * G * NB * 4); // 16 KB
    double*   dsum     = (double*)((char*)cnt + (size_t)NB * 4);            // 32 KB

    loss_hist_k<<<G, 256, 0, stream>>>(pred, target, priv_cnt, priv_sum, N);
    reduce_k<<<NB / 256, 256, 0, stream>>>(priv_cnt, priv_sum, cnt, dsum);
    scan_k<<<1, 256, 0, stream>>>(cnt, dsum, (float*)d_out, K);
}